// Round 1
// baseline (314.610 us; speedup 1.0000x reference)
//
#include <hip/hip_runtime.h>

// B=4, C=256, C8=32, N=4096. fp16 MFMA: 16x16x32 (S, proj), 32x32x16 (PV).
#define BB 4
#define CC 256
#define NN 4096

typedef _Float16 half_t;
typedef __attribute__((ext_vector_type(8))) _Float16 half8;
typedef __attribute__((ext_vector_type(4))) _Float16 half4;
typedef __attribute__((ext_vector_type(4))) float floatx4;
typedef __attribute__((ext_vector_type(16))) float floatx16;

// ---------------------------------------------------------------------------
// cvt_w: cast the six weight matrices to fp16. grid (64, 6).
// ---------------------------------------------------------------------------
__global__ __launch_bounds__(256)
void cvt_w_kernel(const float* __restrict__ Wfx, const float* __restrict__ Wgx,
                  const float* __restrict__ Whx, const float* __restrict__ Wfy,
                  const float* __restrict__ Wgy, const float* __restrict__ Why,
                  half_t* __restrict__ oWfx, half_t* __restrict__ oWgx,
                  half_t* __restrict__ oWhx, half_t* __restrict__ oWfy,
                  half_t* __restrict__ oWgy, half_t* __restrict__ oWhy)
{
    const float* src; half_t* dst; int n;
    switch (blockIdx.y) {
        case 0: src = Wfx; dst = oWfx; n = 32 * CC; break;
        case 1: src = Wgx; dst = oWgx; n = 32 * CC; break;
        case 2: src = Whx; dst = oWhx; n = CC * CC; break;
        case 3: src = Wfy; dst = oWfy; n = 32 * CC; break;
        case 4: src = Wgy; dst = oWgy; n = 32 * CC; break;
        default: src = Why; dst = oWhy; n = CC * CC; break;
    }
    int idx = (blockIdx.x * 256 + threadIdx.x) * 4;
    if (idx >= n) return;
    float4 v = *(const float4*)&src[idx];
    half4 h; h[0] = (half_t)v.x; h[1] = (half_t)v.y; h[2] = (half_t)v.z; h[3] = (half_t)v.w;
    *(half4*)&dst[idx] = h;
}

// ---------------------------------------------------------------------------
// transpose_cvt: xT[b][n][c] fp16 from in[b][c][n] fp32. grid (64, 4, 8).
// ---------------------------------------------------------------------------
__global__ __launch_bounds__(256)
void transpose_cvt_kernel(const float* __restrict__ x, const float* __restrict__ y,
                          half_t* __restrict__ xTx, half_t* __restrict__ xTy)
{
    const int n0 = blockIdx.x * 64;
    const int c0 = blockIdx.y * 64;
    const int b  = blockIdx.z & 3;
    const int sel = blockIdx.z >> 2;
    const float* in = sel ? y : x;
    half_t* outT = sel ? xTy : xTx;
    const int t  = threadIdx.x;
    const int ch = t & 7, nl = t >> 3;            // 8 c-chunks x 32 n
    const float* inb = in + (size_t)b * CC * NN;
    half_t* outb = outT + (size_t)b * NN * CC;

    #pragma unroll
    for (int p = 0; p < 2; ++p) {
        int n = n0 + nl + 32 * p;
        half8 hv;
        #pragma unroll
        for (int j = 0; j < 8; ++j)
            hv[j] = (half_t)inb[(size_t)(c0 + 8 * ch + j) * NN + n];
        *(half8*)&outb[(size_t)n * CC + c0 + 8 * ch] = hv;
    }
}

// ---------------------------------------------------------------------------
// proj_fg (MFMA): fT[n][32], gT[n][32]. grid (64, 4, 2): z = sel.
// ---------------------------------------------------------------------------
__global__ __launch_bounds__(256)
void proj_fg_kernel(const half_t* __restrict__ xTx, const half_t* __restrict__ xTy,
                    const half_t* __restrict__ Wfx, const half_t* __restrict__ Wgx,
                    const half_t* __restrict__ Wfy, const half_t* __restrict__ Wgy,
                    const float* __restrict__ bfx, const float* __restrict__ bgx,
                    const float* __restrict__ bfy, const float* __restrict__ bgy,
                    half_t* __restrict__ fxT, half_t* __restrict__ gxT,
                    half_t* __restrict__ fyT, half_t* __restrict__ gyT)
{
    const int n0 = blockIdx.x * 64;
    const int b  = blockIdx.y;
    const int sel = blockIdx.z;
    const half_t* xT = sel ? xTy : xTx;
    const half_t* Wf = sel ? Wfy : Wfx;
    const half_t* Wg = sel ? Wgy : Wgx;
    const float*  bf = sel ? bfy : bfx;
    const float*  bg = sel ? bgy : bgx;
    half_t* fT = sel ? fyT : fxT;
    half_t* gT = sel ? gyT : gxT;

    const int t  = threadIdx.x;
    const int w = t >> 6, lane = t & 63, q = lane >> 4, mc = lane & 15;
    const half_t* xTb = xT + (size_t)b * NN * CC;

    floatx4 acc[4];
    #pragma unroll
    for (int i = 0; i < 4; ++i) {
        float bv = (i < 2 ? bf : bg)[(i & 1) * 16 + mc];
        acc[i] = (floatx4){bv, bv, bv, bv};
    }

    #pragma unroll
    for (int ks = 0; ks < 8; ++ks) {
        int k0 = ks * 32 + q * 8;
        half8 af = *(const half8*)&xTb[(size_t)(n0 + w * 16 + mc) * CC + k0];
        #pragma unroll
        for (int i = 0; i < 4; ++i) {
            const half_t* Ws = (i < 2) ? Wf : Wg;
            half8 bfr = *(const half8*)&Ws[(size_t)((i & 1) * 16 + mc) * CC + k0];
            acc[i] = __builtin_amdgcn_mfma_f32_16x16x32_f16(af, bfr, acc[i], 0, 0, 0);
        }
    }

    #pragma unroll
    for (int i = 0; i < 4; ++i) {
        half_t* dst = (i < 2) ? fT : gT;
        #pragma unroll
        for (int r = 0; r < 4; ++r) {
            int n = n0 + w * 16 + q * 4 + r;
            dst[((size_t)b * NN + n) * 32 + (i & 1) * 16 + mc] = (half_t)acc[i][r];
        }
    }
}

// ---------------------------------------------------------------------------
// proj_h (MFMA): h[o][n] plain layout (R4-verified). grid (64, 2, 8).
// ---------------------------------------------------------------------------
__global__ __launch_bounds__(256)
void proj_h_kernel(const half_t* __restrict__ xTx, const half_t* __restrict__ xTy,
                   const half_t* __restrict__ Whx, const half_t* __restrict__ Why,
                   const float* __restrict__ bhx, const float* __restrict__ bhy,
                   half_t* __restrict__ hx, half_t* __restrict__ hy)
{
    const int n0 = blockIdx.x * 64;
    const int o0 = blockIdx.y * 128;
    const int b  = blockIdx.z & 3;
    const int sel = blockIdx.z >> 2;
    const half_t* xT = sel ? xTy : xTx;
    const half_t* Wh = sel ? Why : Whx;
    const float*  bh = sel ? bhy : bhx;
    half_t* h = sel ? hy : hx;

    const int t  = threadIdx.x;
    const int w = t >> 6, lane = t & 63, q = lane >> 4, mc = lane & 15;
    const half_t* xTb = xT + (size_t)b * NN * CC;
    half_t* hb = h + (size_t)b * CC * NN;

    floatx4 acc[2][4];
    #pragma unroll
    for (int j = 0; j < 2; ++j) {
        floatx4 bv;
        #pragma unroll
        for (int r = 0; r < 4; ++r) bv[r] = bh[o0 + w * 32 + j * 16 + q * 4 + r];
        #pragma unroll
        for (int i = 0; i < 4; ++i) acc[j][i] = bv;
    }

    #pragma unroll
    for (int ks = 0; ks < 8; ++ks) {
        int k0 = ks * 32 + q * 8;
        half8 a0 = *(const half8*)&Wh[(size_t)(o0 + w * 32 + mc) * CC + k0];
        half8 a1 = *(const half8*)&Wh[(size_t)(o0 + w * 32 + 16 + mc) * CC + k0];
        #pragma unroll
        for (int i = 0; i < 4; ++i) {
            half8 bfr = *(const half8*)&xTb[(size_t)(n0 + i * 16 + mc) * CC + k0];
            acc[0][i] = __builtin_amdgcn_mfma_f32_16x16x32_f16(a0, bfr, acc[0][i], 0, 0, 0);
            acc[1][i] = __builtin_amdgcn_mfma_f32_16x16x32_f16(a1, bfr, acc[1][i], 0, 0, 0);
        }
    }

    #pragma unroll
    for (int j = 0; j < 2; ++j)
        #pragma unroll
        for (int i = 0; i < 4; ++i)
            #pragma unroll
            for (int r = 0; r < 4; ++r) {
                int o = o0 + w * 32 + j * 16 + q * 4 + r;
                hb[(size_t)o * NN + n0 + i * 16 + mc] = (half_t)acc[j][i][r];
            }
}

// ---------------------------------------------------------------------------
// stats: Llog2[n] = -log2( sum_m exp(S[n,m]) ). grid (128, 4, 2).
// ---------------------------------------------------------------------------
__global__ __launch_bounds__(256)
void stats_kernel(const half_t* __restrict__ fT0, const half_t* __restrict__ gT0,
                  const half_t* __restrict__ fT1, const half_t* __restrict__ gT1,
                  float* __restrict__ L0, float* __restrict__ L1)
{
    __shared__ float red_l[4][32];
    const int b  = blockIdx.y;
    const int sel = blockIdx.z;
    const half_t* fT = sel ? fT1 : fT0;
    const half_t* gT = sel ? gT1 : gT0;
    float* Lout = sel ? L1 : L0;

    const int n0 = blockIdx.x * 32;
    const int t  = threadIdx.x;
    const int w = t >> 6, lane = t & 63, q = lane >> 4, mc = lane & 15;
    const half_t* fTb = fT + (size_t)b * NN * 32;
    const half_t* gTb = gT + (size_t)b * NN * 32;

    half8 a0 = *(const half8*)&fTb[(size_t)(n0 + mc) * 32 + q * 8];
    half8 a1 = *(const half8*)&fTb[(size_t)(n0 + 16 + mc) * 32 + q * 8];

    float l0[4] = {0.f, 0.f, 0.f, 0.f}, l1[4] = {0.f, 0.f, 0.f, 0.f};
    for (int it = 0; it < NN / 64; ++it) {
        int m = (it * 4 + w) * 16 + mc;
        half8 bfr = *(const half8*)&gTb[(size_t)m * 32 + q * 8];
        floatx4 S0 = __builtin_amdgcn_mfma_f32_16x16x32_f16(a0, bfr, (floatx4){0.f,0.f,0.f,0.f}, 0, 0, 0);
        floatx4 S1 = __builtin_amdgcn_mfma_f32_16x16x32_f16(a1, bfr, (floatx4){0.f,0.f,0.f,0.f}, 0, 0, 0);
        #pragma unroll
        for (int r = 0; r < 4; ++r) { l0[r] += __expf(S0[r]); l1[r] += __expf(S1[r]); }
    }
    #pragma unroll
    for (int r = 0; r < 4; ++r) {
        #pragma unroll
        for (int off = 1; off < 16; off <<= 1) {
            l0[r] += __shfl_xor(l0[r], off);
            l1[r] += __shfl_xor(l1[r], off);
        }
    }
    if (mc == 0)
        #pragma unroll
        for (int r = 0; r < 4; ++r) {
            red_l[w][q * 4 + r]      = l0[r];
            red_l[w][16 + q * 4 + r] = l1[r];
        }
    __syncthreads();
    if (t < 32) {
        float L = red_l[0][t] + red_l[1][t] + red_l[2][t] + red_l[3][t];
        Lout[(size_t)b * NN + n0 + t] = -log2f(L);
    }
}

// ---------------------------------------------------------------------------
// pv: out[c,m] = src[c,m] + gamma * sum_n h[c,n] * exp2(S*log2e + Llog2[n]).
// v2: 512 threads (8 waves), double-buffered PT/h_lds -> ONE barrier per
// K-tile; XOR chunk-swizzled LDS (pitch 64, chunk^=row&7) on both write and
// read sides -> conflict-free ds_read_b128. grid (32, 2, 8), tile 128c x 128m.
// S phase: wave w computes PT rows w*16..w*16+15 over the 64-n tile.
// PV: wave w: c-half ca=(w>>2)*64, m-quarter mb=(w&3)*32; 32x32x16, acc[2].
// Segment i: {issue tile-(i+1) global loads | PV(i) from buf[i&1] |
//             stage h + S -> buf[(i+1)&1]} ; __syncthreads().
// ---------------------------------------------------------------------------
__global__ __launch_bounds__(512, 4)
void pv_kernel(const half_t* __restrict__ fT0, const half_t* __restrict__ gT0,
               const half_t* __restrict__ h0, const float* __restrict__ L0,
               const float* __restrict__ src0, float* __restrict__ out0,
               const half_t* __restrict__ fT1, const half_t* __restrict__ gT1,
               const half_t* __restrict__ h1, const float* __restrict__ L1,
               const float* __restrict__ src1, float* __restrict__ out1,
               const float* __restrict__ gamma)
{
    __shared__ half_t h_lds[2][128][64];   // 32 KB, swizzled chunks
    __shared__ half_t PT[2][128][64];      // 32 KB, P^T[m][n], swizzled chunks

    const int m0 = blockIdx.x * 128;
    const int c0 = blockIdx.y * 128;
    const int b  = blockIdx.z & 3;
    const int sel = blockIdx.z >> 2;
    const half_t* fT = sel ? fT1 : fT0;
    const half_t* gT = sel ? gT1 : gT0;
    const half_t* h  = sel ? h1 : h0;
    const float*  Lg = sel ? L1 : L0;
    const float*  src = sel ? src1 : src0;
    float* out = sel ? out1 : out0;

    const int t = threadIdx.x;
    const int w = t >> 6, lane = t & 63;
    const int q = lane >> 4, mc = lane & 15;
    const int l5 = lane >> 5, l31 = lane & 31;

    const half_t* fTb = fT + (size_t)b * NN * 32;
    const half_t* gTb = gT + (size_t)b * NN * 32;
    const half_t* hb  = h + (size_t)b * CC * NN;
    const float*  Lb  = Lg + (size_t)b * NN;

    // persistent S B-frag: m = m0 + w*16 + mc (wave w owns PT rows w*16..+15)
    const half8 gS = *(const half8*)&gTb[(size_t)(m0 + w * 16 + mc) * 32 + q * 8];

    // h staging: thread t covers rows {sr, sr+64}, LDS chunk sj; the LDS slot
    // sj of row r holds GLOBAL chunk sj^(r&7)  (pre-swizzled source, T2/#21).
    const int sj = t & 7;          // LDS chunk 0..7 (16B units)
    const int sr = t >> 3;         // 0..63
    const int sjx = sj ^ (sr & 7); // global chunk ((sr+64)&7 == sr&7)

    // PV wave tile
    const int ca = (w >> 2) * 64;     // c-half
    const int mb = (w & 3) * 32;      // m-quarter
    const int swzr = l31 & 7;

    floatx16 acc[2];
    #pragma unroll
    for (int a = 0; a < 2; ++a)
        #pragma unroll
        for (int r = 0; r < 16; ++r) acc[a][r] = 0.f;

    // ---- prologue: tile 0 into buf 0
    {
        half8 hg0 = *(const half8*)&hb[(size_t)(c0 + sr) * NN + sjx * 8];
        half8 hg1 = *(const half8*)&hb[(size_t)(c0 + sr + 64) * NN + sjx * 8];
        half8 af[4]; float4 lv[4];
        #pragma unroll
        for (int s = 0; s < 4; ++s) {
            af[s] = *(const half8*)&fTb[(size_t)(s * 16 + mc) * 32 + q * 8];
            lv[s] = *(const float4*)&Lb[s * 16 + q * 4];
        }
        *(half8*)&h_lds[0][sr][sj * 8]      = hg0;
        *(half8*)&h_lds[0][sr + 64][sj * 8] = hg1;
        #pragma unroll
        for (int s = 0; s < 4; ++s) {
            floatx4 S = __builtin_amdgcn_mfma_f32_16x16x32_f16(
                af[s], gS, (floatx4){0.f, 0.f, 0.f, 0.f}, 0, 0, 0);
            half4 p;
            p[0] = (half_t)exp2f(fmaf(S[0], 1.44269504f, lv[s].x));
            p[1] = (half_t)exp2f(fmaf(S[1], 1.44269504f, lv[s].y));
            p[2] = (half_t)exp2f(fmaf(S[2], 1.44269504f, lv[s].z));
            p[3] = (half_t)exp2f(fmaf(S[3], 1.44269504f, lv[s].w));
            *(half4*)&PT[0][w * 16 + mc]
                [(((2 * s + (q >> 1)) ^ (mc & 7)) << 3) + ((q & 1) << 2)] = p;
        }
    }
    __syncthreads();

    for (int it = 0; it < NN / 64; ++it) {
        const int cur = it & 1, nxt = cur ^ 1;
        int ntn = (it + 1) * 64; if (ntn >= NN) ntn = 0;   // wrap: wasted, harmless

        // ---- issue next-tile global loads (latency hides under PV)
        half8 hg0 = *(const half8*)&hb[(size_t)(c0 + sr) * NN + ntn + sjx * 8];
        half8 hg1 = *(const half8*)&hb[(size_t)(c0 + sr + 64) * NN + ntn + sjx * 8];
        half8 af[4]; float4 lv[4];
        #pragma unroll
        for (int s = 0; s < 4; ++s) {
            af[s] = *(const half8*)&fTb[(size_t)(ntn + s * 16 + mc) * 32 + q * 8];
            lv[s] = *(const float4*)&Lb[ntn + s * 16 + q * 4];
        }

        // ---- PV(it): 4 k-chunks of 16; 2 MFMA32 each, swizzled reads
        #pragma unroll
        for (int ch = 0; ch < 4; ++ch) {
            const int cidx = ((2 * ch + l5) ^ swzr) << 3;
            half8 Bf = *(const half8*)&PT[cur][mb + l31][cidx];
            half8 A0 = *(const half8*)&h_lds[cur][ca + l31][cidx];
            half8 A1 = *(const half8*)&h_lds[cur][ca + 32 + l31][cidx];
            acc[0] = __builtin_amdgcn_mfma_f32_32x32x16_f16(A0, Bf, acc[0], 0, 0, 0);
            acc[1] = __builtin_amdgcn_mfma_f32_32x32x16_f16(A1, Bf, acc[1], 0, 0, 0);
        }

        // ---- stage h(it+1) + S(it+1) into buf nxt
        *(half8*)&h_lds[nxt][sr][sj * 8]      = hg0;
        *(half8*)&h_lds[nxt][sr + 64][sj * 8] = hg1;
        #pragma unroll
        for (int s = 0; s < 4; ++s) {
            floatx4 S = __builtin_amdgcn_mfma_f32_16x16x32_f16(
                af[s], gS, (floatx4){0.f, 0.f, 0.f, 0.f}, 0, 0, 0);
            half4 p;
            p[0] = (half_t)exp2f(fmaf(S[0], 1.44269504f, lv[s].x));
            p[1] = (half_t)exp2f(fmaf(S[1], 1.44269504f, lv[s].y));
            p[2] = (half_t)exp2f(fmaf(S[2], 1.44269504f, lv[s].z));
            p[3] = (half_t)exp2f(fmaf(S[3], 1.44269504f, lv[s].w));
            *(half4*)&PT[nxt][w * 16 + mc]
                [(((2 * s + (q >> 1)) ^ (mc & 7)) << 3) + ((q & 1) << 2)] = p;
        }
        __syncthreads();
    }

    // ---- epilogue: out = src + gamma * acc (D: col=l31->m, row pattern->c)
    const float gm = gamma[0];
    const float* srcb = src + (size_t)b * CC * NN;
    float* outb = out + (size_t)b * CC * NN;
    const int m = m0 + mb + l31;
    #pragma unroll
    for (int a = 0; a < 2; ++a)
        #pragma unroll
        for (int r = 0; r < 16; ++r) {
            int c = c0 + ca + a * 32 + (r & 3) + 8 * (r >> 2) + 4 * l5;
            size_t idx = (size_t)c * NN + m;
            outb[idx] = fmaf(gm, acc[a][r], srcb[idx]);
        }
}

// ---------------------------------------------------------------------------
extern "C" void kernel_launch(void* const* d_in, const int* in_sizes, int n_in,
                              void* d_out, int out_size, void* d_ws, size_t ws_size,
                              hipStream_t stream)
{
    const float* x   = (const float*)d_in[0];
    const float* y   = (const float*)d_in[1];
    const float* Wfx = (const float*)d_in[2];
    const float* bfx = (const float*)d_in[3];
    const float* Wgx = (const float*)d_in[4];
    const float* bgx = (const float*)d_in[5];
    const float* Whx = (const float*)d_in[6];
    const float* bhx = (const float*)d_in[7];
    const float* Wfy = (const float*)d_in[8];
    const float* bfy = (const float*)d_in[9];
    const float* Wgy = (const float*)d_in[10];
    const float* bgy = (const float*)d_in[11];
    const float* Why = (const float*)d_in[12];
    const float* bhy = (const float*)d_in[13];
    const float* gam = (const float*)d_in[14];

    const size_t SZ_XT = (size_t)BB * NN * CC;   // 4,194,304 halves
    const size_t SZ_FG = (size_t)BB * NN * 32;   // 524,288 halves
    half_t* xTx   = (half_t*)d_ws;
    half_t* xTy   = xTx + SZ_XT;
    half_t* hx    = xTy + SZ_XT;
    half_t* hy    = hx + SZ_XT;
    half_t* fxT   = hy + SZ_XT;
    half_t* gxT   = fxT + SZ_FG;
    half_t* fyT   = gxT + SZ_FG;
    half_t* gyT   = fyT + SZ_FG;
    half_t* Wfx_h = gyT + SZ_FG;
    half_t* Wgx_h = Wfx_h + 32 * CC;
    half_t* Wfy_h = Wgx_h + 32 * CC;
    half_t* Wgy_h = Wfy_h + 32 * CC;
    half_t* Whx_h = Wgy_h + 32 * CC;
    half_t* Why_h = Whx_h + CC * CC;
    float*  Lx    = (float*)(Why_h + CC * CC);
    float*  Ly    = Lx + (size_t)BB * NN;

    float* outx = (float*)d_out;
    float* outy = outx + (size_t)BB * CC * NN;

    cvt_w_kernel<<<dim3(64, 6), 256, 0, stream>>>(Wfx, Wgx, Whx, Wfy, Wgy, Why,
                                                  Wfx_h, Wgx_h, Whx_h, Wfy_h, Wgy_h, Why_h);

    transpose_cvt_kernel<<<dim3(64, 4, 8), 256, 0, stream>>>(x, y, xTx, xTy);

    proj_fg_kernel<<<dim3(64, 4, 2), 256, 0, stream>>>(
        xTx, xTy, Wfx_h, Wgx_h, Wfy_h, Wgy_h, bfx, bgx, bfy, bgy, fxT, gxT, fyT, gyT);

    proj_h_kernel<<<dim3(64, 2, 8), 256, 0, stream>>>(
        xTx, xTy, Whx_h, Why_h, bhx, bhy, hx, hy);

    // att_x rows: fy vs gx -> Lx ; att_y rows: fx vs gy -> Ly
    stats_kernel<<<dim3(128, 4, 2), 256, 0, stream>>>(fyT, gxT, fxT, gyT, Lx, Ly);

    pv_kernel<<<dim3(32, 2, 8), 512, 0, stream>>>(
        fyT, gxT, hx, Lx, x, outx,
        fxT, gyT, hy, Ly, y, outy, gam);
}